// Round 8
// baseline (139.856 us; speedup 1.0000x reference)
//
#include <hip/hip_runtime.h>

#define HH 181
#define WW 360
#define NPIX (HH*WW)        // 65160
#define NCH 16
#define NHID 256
#define NPIX16 (NCH*NPIX)   // 1042560
#define NG4 (NPIX16/4)      // 260640 4-wide groups (exact)
#define NPG4 (NPIX/4)       // 16290 pixel groups
#define GPR (WW/4)          // 90 groups per row
#define GPC (NPIX/4)        // 16290 groups per channel
#define EPITOL 1e-5f
#define NTERMS 19

// K1: q[o,pix] = sum_c W_down[o,c] * hidden[c,pix] + b_down[o].
// W_down transposed into LDS per block (uniform broadcast reads); flags
// zeroing folded in (block 0).
__global__ __launch_bounds__(256) void down_kernel(const float* __restrict__ hid,
                                                   const float* __restrict__ Wd,
                                                   const float* __restrict__ b_down,
                                                   float* __restrict__ q,
                                                   unsigned* __restrict__ flags) {
    __shared__ float sWT[NHID * NCH];   // 16 KB: sWT[c*16+o] = Wd[o*256+c]
    if (blockIdx.x == 0 && threadIdx.x < 64) flags[threadIdx.x] = 0u;
    for (int i = threadIdx.x; i < NCH * NHID; i += 256) {
        int o = i >> 8, c = i & 255;
        sWT[c * NCH + o] = Wd[i];
    }
    __syncthreads();
    int pix = blockIdx.x * 256 + threadIdx.x;
    if (pix >= NPIX) return;
    float acc[NCH];
#pragma unroll
    for (int o = 0; o < NCH; ++o) acc[o] = b_down[o];
#pragma unroll 8
    for (int c = 0; c < NHID; ++c) {
        float hv = hid[c * NPIX + pix];
#pragma unroll
        for (int o = 0; o < NCH; ++o) acc[o] += sWT[c * NCH + o] * hv;
    }
#pragma unroll
    for (int o = 0; o < NCH; ++o) q[o * NPIX + pix] = acc[o];
}

// K2 (x20): one upwind pass, 4 consecutive w per thread, all-float4 traffic.
// Deferred result accumulation: pass 0 stores nt0; even passes k>=2 RMW
// result += center_tap(nt_{k-1}) + nt_k; odd passes skip result; pass 19
// RMW += own only. Every computed term lands exactly once; a pending odd
// term at the early stop is dropped — exactly the reference's exclusion of
// the first small term. Pass k>=2 skips whole-grid when flags[k-1]==0.
__global__ __launch_bounds__(256) void pass_kernel(
        const float* __restrict__ tin,
        float* __restrict__ tout,
        const float* __restrict__ u,
        const float* __restrict__ v,
        float* __restrict__ result,
        const float* __restrict__ dt_p,
        const float* __restrict__ dlon_p,
        const float* __restrict__ dlat_p,
        unsigned* __restrict__ flags,
        int k) {
    if (k >= 2) {
        if (flags[k - 1] == 0u) return;   // uniform: whole grid skips together
    }
    const float cp0 = -2.0f/60.0f, cp1 = 15.0f/60.0f, cp2 = -60.0f/60.0f,
                cp3 = 20.0f/60.0f, cp4 = 30.0f/60.0f, cp5 = -3.0f/60.0f;
    const float cn0 =  3.0f/60.0f, cn1 = -30.0f/60.0f, cn2 = -20.0f/60.0f,
                cn3 = 60.0f/60.0f, cn4 = -15.0f/60.0f, cn5 =  2.0f/60.0f;

    const int g4 = blockIdx.x * 256 + threadIdx.x;
    float m = 0.0f;
    if (g4 < NG4) {
        const float inv_dlon = 1.0f / dlon_p[0];
        const float inv_dlat = 1.0f / dlat_p[0];
        const float scale = (k == 0) ? 1.0f : dt_p[0] / (float)(k + 1);

        const int ch  = g4 / GPC;
        const int rem = g4 - ch * GPC;
        const int h   = rem / GPR;
        const int bi  = rem - h * GPR;     // float4 block index in row, 0..89
        const int w0  = bi * 4;

        const float* base = tin + ch * NPIX;
        // lon window: cols w0-4 .. w0+7 as 3 aligned float4 (cyclic by block)
        const float4* rowv = (const float4*)(base + h * WW);
        float4 Af = rowv[bi == 0 ? GPR - 1 : bi - 1];
        float4 Bf = rowv[bi];
        float4 Cf = rowv[bi == GPR - 1 ? 0 : bi + 1];
        float Wn[12] = {Af.x, Af.y, Af.z, Af.w, Bf.x, Bf.y, Bf.z, Bf.w,
                        Cf.x, Cf.y, Cf.z, Cf.w};
        // lat taps: rows h-3..h+3 (pole mirror -> flipped col base, still x4-aligned)
        const int wf0 = (w0 >= WW / 2) ? (w0 - WW / 2) : (w0 + WW / 2);
        float S[7][4];
#pragma unroll
        for (int d = 0; d < 7; ++d) {
            int rr = h + d - 3;
            int cb = w0;
            if (rr < 0)           { rr = -1 - rr;        cb = wf0; }
            else if (rr > HH - 1) { rr = 2*HH - 1 - rr;  cb = wf0; }
            float4 t = *(const float4*)(base + rr * WW + cb);
            S[d][0] = t.x; S[d][1] = t.y; S[d][2] = t.z; S[d][3] = t.w;
        }
        const int gi = ch * NPIX + h * WW + w0;
        float4 Uf = *(const float4*)(u + gi);
        float4 Vf = *(const float4*)(v + gi);
        const float Ua[4] = {Uf.x, Uf.y, Uf.z, Uf.w};
        const float Va[4] = {Vf.x, Vf.y, Vf.z, Vf.w};

        float o4[4];
#pragma unroll
        for (int j = 0; j < 4; ++j) {
            float dpl = cp0*Wn[j+1] + cp1*Wn[j+2] + cp2*Wn[j+3]
                      + cp3*Wn[j+4] + cp4*Wn[j+5] + cp5*Wn[j+6];
            float dnl = cn0*Wn[j+2] + cn1*Wn[j+3] + cn2*Wn[j+4]
                      + cn3*Wn[j+5] + cn4*Wn[j+6] + cn5*Wn[j+7];
            float dpa = cp0*S[0][j] + cp1*S[1][j] + cp2*S[2][j]
                      + cp3*S[3][j] + cp4*S[4][j] + cp5*S[5][j];
            float dna = cn0*S[1][j] + cn1*S[2][j] + cn2*S[3][j]
                      + cn3*S[4][j] + cn4*S[5][j] + cn5*S[6][j];
            float uu = Ua[j], vv = Va[j];
            float nt = (-uu * ((uu > 0.0f ? dpl : dnl) * inv_dlon)
                        -vv * ((vv > 0.0f ? dpa : dna) * inv_dlat)) * scale;
            o4[j] = nt;
            m = fmaxf(m, fabsf(nt));
        }
        if (k < NTERMS)   // pass 19's term buffer is never read
            *(float4*)(tout + gi) = make_float4(o4[0], o4[1], o4[2], o4[3]);

        if (k == 0) {
            *(float4*)(result + gi) = make_float4(o4[0], o4[1], o4[2], o4[3]);
        } else if (k == NTERMS) {          // last pass: own term only
            float4 R = *(const float4*)(result + gi);
            R.x += o4[0]; R.y += o4[1]; R.z += o4[2]; R.w += o4[3];
            *(float4*)(result + gi) = R;
        } else if ((k & 1) == 0) {         // even pass: predecessor + own
            float4 R = *(const float4*)(result + gi);
            R.x += Bf.x + o4[0]; R.y += Bf.y + o4[1];
            R.z += Bf.z + o4[2]; R.w += Bf.w + o4[3];
            *(float4*)(result + gi) = R;
        }                                  // odd pass < 19: deferred
    }
    if (k >= 1 && k < NTERMS) {
        __shared__ float wmax[4];
#pragma unroll
        for (int s = 32; s >= 1; s >>= 1) m = fmaxf(m, __shfl_xor(m, s));
        if ((threadIdx.x & 63) == 0) wmax[threadIdx.x >> 6] = m;
        __syncthreads();
        if (threadIdx.x == 0) {
            float bm = fmaxf(fmaxf(wmax[0], wmax[1]), fmaxf(wmax[2], wmax[3]));
            if (bm >= EPITOL) flags[k] = 1u;   // plain store, no atomic
        }
    }
}

// K3: out[c,pix] = sum_o W_up[c,o]*dwc[o,pix] + b_up[c], dwc inline:
// dwc = (q + result*dt)*dw[o] + db[o]. 4 pixels/thread, float4 everywhere;
// Wu chunk (32x16) staged in LDS. Grid 64 x 8 = 512 blocks.
__global__ __launch_bounds__(256) void up_kernel(const float* __restrict__ q,
                                                 const float* __restrict__ result,
                                                 const float* __restrict__ dt_p,
                                                 const float* __restrict__ dw,
                                                 const float* __restrict__ db,
                                                 const float* __restrict__ Wu,
                                                 const float* __restrict__ b_up,
                                                 float* __restrict__ out) {
    __shared__ float sW[32 * NCH];   // Wu[c0+cc][o]
    const int c0 = blockIdx.y * 32;
    for (int i = threadIdx.x; i < 32 * NCH; i += 256) sW[i] = Wu[c0 * NCH + i];
    __syncthreads();

    const int g = blockIdx.x * 256 + threadIdx.x;
    if (g >= NPG4) return;
    const int pix0 = g * 4;
    const float dt = dt_p[0];

    float d[NCH][4];
#pragma unroll
    for (int o = 0; o < NCH; ++o) {
        const int gb = o * NPIX + pix0;
        float4 Q = *(const float4*)(q + gb);
        float4 R = *(const float4*)(result + gb);
        float dwo = dw[o], dbo = db[o];
        d[o][0] = (Q.x + R.x * dt) * dwo + dbo;
        d[o][1] = (Q.y + R.y * dt) * dwo + dbo;
        d[o][2] = (Q.z + R.z * dt) * dwo + dbo;
        d[o][3] = (Q.w + R.w * dt) * dwo + dbo;
    }
#pragma unroll 4
    for (int cc = 0; cc < 32; ++cc) {
        const int c = c0 + cc;
        const float bc = b_up[c];
        float a0 = bc, a1 = bc, a2 = bc, a3 = bc;
#pragma unroll
        for (int o = 0; o < NCH; ++o) {
            float wv = sW[cc * NCH + o];
            a0 += wv * d[o][0]; a1 += wv * d[o][1];
            a2 += wv * d[o][2]; a3 += wv * d[o][3];
        }
        *(float4*)(out + c * NPIX + pix0) = make_float4(a0, a1, a2, a3);
    }
}

extern "C" void kernel_launch(void* const* d_in, const int* in_sizes, int n_in,
                              void* d_out, int out_size, void* d_ws, size_t ws_size,
                              hipStream_t stream) {
    const float* hidden = (const float*)d_in[0];   // (1,256,181,360)
    const float* u      = (const float*)d_in[1];   // (1,16,181,360)
    const float* v      = (const float*)d_in[2];   // (1,16,181,360)
    const float* dt_p   = (const float*)d_in[3];   // scalar
    const float* dlat_p = (const float*)d_in[4];   // scalar
    const float* dlon_p = (const float*)d_in[5];   // scalar
    const float* W_down = (const float*)d_in[6];   // (16,256)
    const float* b_down = (const float*)d_in[7];   // (16,)
    const float* dw     = (const float*)d_in[8];   // (16,)
    const float* db     = (const float*)d_in[9];   // (16,)
    const float* W_up   = (const float*)d_in[10];  // (256,16)
    const float* b_up   = (const float*)d_in[11];  // (256,)
    float* out = (float*)d_out;

    float* ws = (float*)d_ws;
    float* q      = ws;
    float* t0     = ws + (size_t)NPIX16;
    float* t1     = ws + (size_t)2 * NPIX16;
    float* result = ws + (size_t)3 * NPIX16;
    unsigned* flags = (unsigned*)(ws + (size_t)4 * NPIX16);

    const int nbp = (NPIX + 255) / 256;   // 255
    const int nbg = (NG4 + 255) / 256;    // 1019
    const int nbu = (NPG4 + 255) / 256;   // 64

    down_kernel<<<nbp, 256, 0, stream>>>(hidden, W_down, b_down, q, flags);

    // pass 0 (F_n) + passes 1..19, ping-ponging term buffers
    pass_kernel<<<nbg, 256, 0, stream>>>(q, t0, u, v, result,
                                         dt_p, dlon_p, dlat_p, flags, 0);
    for (int k = 1; k <= NTERMS; ++k) {
        float* tin  = (k & 1) ? t0 : t1;
        float* tout = (k & 1) ? t1 : t0;
        pass_kernel<<<nbg, 256, 0, stream>>>(tin, tout, u, v, result,
                                             dt_p, dlon_p, dlat_p, flags, k);
    }

    up_kernel<<<dim3(nbu, 8), 256, 0, stream>>>(q, result, dt_p, dw, db,
                                                W_up, b_up, out);
}

// Round 9
// 126.752 us; speedup vs baseline: 1.1034x; 1.1034x over previous
//
#include <hip/hip_runtime.h>

#define HH 181
#define WW 360
#define NPIX (HH*WW)        // 65160
#define NCH 16
#define NHID 256
#define NPIX16 (NCH*NPIX)   // 1042560
#define NG4 (NPIX16/4)      // 260640 4-wide groups (exact)
#define NPG4 (NPIX/4)       // 16290 pixel groups
#define GPR (WW/4)          // 90 groups per row
#define GPC (NPIX/4)        // 16290 groups per channel
#define PAIRG (2*GPC)       // 32580 groups per channel pair
#define EPITOL 1e-5f
#define NTERMS 19

// K0: transpose W_down (16,256) -> (256,16); zero the early-stop flags.
__global__ __launch_bounds__(256) void tr_kernel(const float* __restrict__ Wd,
                                                 float* __restrict__ WdT,
                                                 unsigned* __restrict__ flags) {
    int i = blockIdx.x * 256 + threadIdx.x;
    if (blockIdx.x == 0 && threadIdx.x < 64) flags[threadIdx.x] = 0u;
    if (i < NCH * NHID) {
        int o = i / NHID, c = i - o * NHID;
        WdT[c * NCH + o] = Wd[i];
    }
}

// K1: q[o,pix] = sum_c WdT[c,o] * hidden[c,pix] + b_down[o].
// WdT reads are wave-uniform -> compiler emits s_load (SGPR operands, free).
// unroll 16 keeps ~16 coalesced hid loads in flight (255-block grid is
// latency-limited at 4 waves/CU; need ~9KB in flight per CU).
__global__ __launch_bounds__(256) void down_kernel(const float* __restrict__ hid,
                                                   const float* __restrict__ WdT,
                                                   const float* __restrict__ b_down,
                                                   float* __restrict__ q) {
    int pix = blockIdx.x * 256 + threadIdx.x;
    if (pix >= NPIX) return;
    float acc[NCH];
#pragma unroll
    for (int o = 0; o < NCH; ++o) acc[o] = b_down[o];
#pragma unroll 16
    for (int c = 0; c < NHID; ++c) {
        float hv = hid[c * NPIX + pix];
#pragma unroll
        for (int o = 0; o < NCH; ++o) acc[o] += WdT[c * NCH + o] * hv;
    }
#pragma unroll
    for (int o = 0; o < NCH; ++o) q[o * NPIX + pix] = acc[o];
}

// K2 (x20): one upwind pass, 4 consecutive w per thread, all-float4 traffic.
// XCD-affine: pair = blockIdx.x % 8 -> XCD x always owns channels 2x,2x+1
// (stencils never cross channels, so term halos / u,v / result slices are
// XCD-L2-resident and the mapping repeats every launch).
// Deferred result accumulation: pass 0 stores nt0; even passes k>=2 RMW
// result += center_tap(nt_{k-1}) + nt_k; odd passes skip result; pass 19
// adds own only. Pass k>=2 skips whole-grid when flags[k-1]==0.
__global__ __launch_bounds__(256) void pass_kernel(
        const float* __restrict__ tin,
        float* __restrict__ tout,
        const float* __restrict__ u,
        const float* __restrict__ v,
        float* __restrict__ result,
        const float* __restrict__ dt_p,
        const float* __restrict__ dlon_p,
        const float* __restrict__ dlat_p,
        unsigned* __restrict__ flags,
        int k) {
    if (k >= 2) {
        if (flags[k - 1] == 0u) return;   // uniform: whole grid skips together
    }
    const float cp0 = -2.0f/60.0f, cp1 = 15.0f/60.0f, cp2 = -60.0f/60.0f,
                cp3 = 20.0f/60.0f, cp4 = 30.0f/60.0f, cp5 = -3.0f/60.0f;
    const float cn0 =  3.0f/60.0f, cn1 = -30.0f/60.0f, cn2 = -20.0f/60.0f,
                cn3 = 60.0f/60.0f, cn4 = -15.0f/60.0f, cn5 =  2.0f/60.0f;

    const int pair = blockIdx.x & 7;          // -> XCD (round-robin dispatch)
    const int idx  = (blockIdx.x >> 3) * 256 + threadIdx.x;
    float m = 0.0f;
    if (idx < PAIRG) {
        const int g4 = pair * PAIRG + idx;
        const float inv_dlon = 1.0f / dlon_p[0];
        const float inv_dlat = 1.0f / dlat_p[0];
        const float scale = (k == 0) ? 1.0f : dt_p[0] / (float)(k + 1);

        const int ch  = g4 / GPC;
        const int rem = g4 - ch * GPC;
        const int h   = rem / GPR;
        const int bi  = rem - h * GPR;     // float4 block index in row, 0..89
        const int w0  = bi * 4;

        const float* base = tin + ch * NPIX;
        // lon window: cols w0-4 .. w0+7 as 3 aligned float4 (cyclic by block)
        const float4* rowv = (const float4*)(base + h * WW);
        float4 Af = rowv[bi == 0 ? GPR - 1 : bi - 1];
        float4 Bf = rowv[bi];
        float4 Cf = rowv[bi == GPR - 1 ? 0 : bi + 1];
        float Wn[12] = {Af.x, Af.y, Af.z, Af.w, Bf.x, Bf.y, Bf.z, Bf.w,
                        Cf.x, Cf.y, Cf.z, Cf.w};
        // lat taps: rows h-3..h+3 (pole mirror -> flipped col base, x4-aligned)
        const int wf0 = (w0 >= WW / 2) ? (w0 - WW / 2) : (w0 + WW / 2);
        float S[7][4];
#pragma unroll
        for (int d = 0; d < 7; ++d) {
            int rr = h + d - 3;
            int cb = w0;
            if (rr < 0)           { rr = -1 - rr;        cb = wf0; }
            else if (rr > HH - 1) { rr = 2*HH - 1 - rr;  cb = wf0; }
            float4 t = *(const float4*)(base + rr * WW + cb);
            S[d][0] = t.x; S[d][1] = t.y; S[d][2] = t.z; S[d][3] = t.w;
        }
        const int gi = ch * NPIX + h * WW + w0;
        float4 Uf = *(const float4*)(u + gi);
        float4 Vf = *(const float4*)(v + gi);
        const float Ua[4] = {Uf.x, Uf.y, Uf.z, Uf.w};
        const float Va[4] = {Vf.x, Vf.y, Vf.z, Vf.w};

        float o4[4];
#pragma unroll
        for (int j = 0; j < 4; ++j) {
            float dpl = cp0*Wn[j+1] + cp1*Wn[j+2] + cp2*Wn[j+3]
                      + cp3*Wn[j+4] + cp4*Wn[j+5] + cp5*Wn[j+6];
            float dnl = cn0*Wn[j+2] + cn1*Wn[j+3] + cn2*Wn[j+4]
                      + cn3*Wn[j+5] + cn4*Wn[j+6] + cn5*Wn[j+7];
            float dpa = cp0*S[0][j] + cp1*S[1][j] + cp2*S[2][j]
                      + cp3*S[3][j] + cp4*S[4][j] + cp5*S[5][j];
            float dna = cn0*S[1][j] + cn1*S[2][j] + cn2*S[3][j]
                      + cn3*S[4][j] + cn4*S[5][j] + cn5*S[6][j];
            float uu = Ua[j], vv = Va[j];
            float nt = (-uu * ((uu > 0.0f ? dpl : dnl) * inv_dlon)
                        -vv * ((vv > 0.0f ? dpa : dna) * inv_dlat)) * scale;
            o4[j] = nt;
            m = fmaxf(m, fabsf(nt));
        }
        if (k < NTERMS)   // pass 19's term buffer is never read
            *(float4*)(tout + gi) = make_float4(o4[0], o4[1], o4[2], o4[3]);

        if (k == 0) {
            *(float4*)(result + gi) = make_float4(o4[0], o4[1], o4[2], o4[3]);
        } else if (k == NTERMS) {          // last pass: own term only
            float4 R = *(const float4*)(result + gi);
            R.x += o4[0]; R.y += o4[1]; R.z += o4[2]; R.w += o4[3];
            *(float4*)(result + gi) = R;
        } else if ((k & 1) == 0) {         // even pass: predecessor + own
            float4 R = *(const float4*)(result + gi);
            R.x += Bf.x + o4[0]; R.y += Bf.y + o4[1];
            R.z += Bf.z + o4[2]; R.w += Bf.w + o4[3];
            *(float4*)(result + gi) = R;
        }                                  // odd pass < 19: deferred
    }
    if (k >= 1 && k < NTERMS) {
        __shared__ float wmax[4];
#pragma unroll
        for (int s = 32; s >= 1; s >>= 1) m = fmaxf(m, __shfl_xor(m, s));
        if ((threadIdx.x & 63) == 0) wmax[threadIdx.x >> 6] = m;
        __syncthreads();
        if (threadIdx.x == 0) {
            float bm = fmaxf(fmaxf(wmax[0], wmax[1]), fmaxf(wmax[2], wmax[3]));
            if (bm >= EPITOL) flags[k] = 1u;   // plain store, no atomic
        }
    }
}

// K3: out[c,pix] = sum_o W_up[c,o]*dwc[o,pix] + b_up[c], dwc inline:
// dwc = (q + result*dt)*dw[o] + db[o]. 4 pixels/thread, float4 everywhere;
// Wu reads are wave-uniform -> s_load. Grid 64 x 8 = 512 blocks.
__global__ __launch_bounds__(256) void up_kernel(const float* __restrict__ q,
                                                 const float* __restrict__ result,
                                                 const float* __restrict__ dt_p,
                                                 const float* __restrict__ dw,
                                                 const float* __restrict__ db,
                                                 const float* __restrict__ Wu,
                                                 const float* __restrict__ b_up,
                                                 float* __restrict__ out) {
    const int g = blockIdx.x * 256 + threadIdx.x;
    if (g >= NPG4) return;
    const int pix0 = g * 4;
    const int c0 = blockIdx.y * 32;
    const float dt = dt_p[0];

    float d[NCH][4];
#pragma unroll
    for (int o = 0; o < NCH; ++o) {
        const int gb = o * NPIX + pix0;
        float4 Q = *(const float4*)(q + gb);
        float4 R = *(const float4*)(result + gb);
        float dwo = dw[o], dbo = db[o];
        d[o][0] = (Q.x + R.x * dt) * dwo + dbo;
        d[o][1] = (Q.y + R.y * dt) * dwo + dbo;
        d[o][2] = (Q.z + R.z * dt) * dwo + dbo;
        d[o][3] = (Q.w + R.w * dt) * dwo + dbo;
    }
#pragma unroll 4
    for (int cc = 0; cc < 32; ++cc) {
        const int c = c0 + cc;
        const float bc = b_up[c];
        float a0 = bc, a1 = bc, a2 = bc, a3 = bc;
#pragma unroll
        for (int o = 0; o < NCH; ++o) {
            float wv = Wu[c * NCH + o];   // uniform -> SGPR
            a0 += wv * d[o][0]; a1 += wv * d[o][1];
            a2 += wv * d[o][2]; a3 += wv * d[o][3];
        }
        *(float4*)(out + c * NPIX + pix0) = make_float4(a0, a1, a2, a3);
    }
}

extern "C" void kernel_launch(void* const* d_in, const int* in_sizes, int n_in,
                              void* d_out, int out_size, void* d_ws, size_t ws_size,
                              hipStream_t stream) {
    const float* hidden = (const float*)d_in[0];   // (1,256,181,360)
    const float* u      = (const float*)d_in[1];   // (1,16,181,360)
    const float* v      = (const float*)d_in[2];   // (1,16,181,360)
    const float* dt_p   = (const float*)d_in[3];   // scalar
    const float* dlat_p = (const float*)d_in[4];   // scalar
    const float* dlon_p = (const float*)d_in[5];   // scalar
    const float* W_down = (const float*)d_in[6];   // (16,256)
    const float* b_down = (const float*)d_in[7];   // (16,)
    const float* dw     = (const float*)d_in[8];   // (16,)
    const float* db     = (const float*)d_in[9];   // (16,)
    const float* W_up   = (const float*)d_in[10];  // (256,16)
    const float* b_up   = (const float*)d_in[11];  // (256,)
    float* out = (float*)d_out;

    float* ws = (float*)d_ws;
    float* q      = ws;
    float* t0     = ws + (size_t)NPIX16;
    float* t1     = ws + (size_t)2 * NPIX16;
    float* result = ws + (size_t)3 * NPIX16;
    float* WdT    = ws + (size_t)4 * NPIX16;
    unsigned* flags = (unsigned*)(ws + (size_t)4 * NPIX16 + NCH * NHID);

    const int nbp = (NPIX + 255) / 256;           // 255
    const int nbg = 8 * ((PAIRG + 255) / 256);    // 8 * 128 = 1024
    const int nbu = (NPG4 + 255) / 256;           // 64

    tr_kernel<<<(NCH * NHID + 255) / 256, 256, 0, stream>>>(W_down, WdT, flags);
    down_kernel<<<nbp, 256, 0, stream>>>(hidden, WdT, b_down, q);

    // pass 0 (F_n) + passes 1..19, ping-ponging term buffers
    pass_kernel<<<nbg, 256, 0, stream>>>(q, t0, u, v, result,
                                         dt_p, dlon_p, dlat_p, flags, 0);
    for (int k = 1; k <= NTERMS; ++k) {
        float* tin  = (k & 1) ? t0 : t1;
        float* tout = (k & 1) ? t1 : t0;
        pass_kernel<<<nbg, 256, 0, stream>>>(tin, tout, u, v, result,
                                             dt_p, dlon_p, dlat_p, flags, k);
    }

    up_kernel<<<dim3(nbu, 8), 256, 0, stream>>>(q, result, dt_p, dw, db,
                                                W_up, b_up, out);
}